// Round 21
// baseline (268.642 us; speedup 1.0000x reference)
//
#include <hip/hip_runtime.h>

#define NTA 65536
#define NC 1024
#define NO 256
#define HDIM 332
#define HP 352          // H padded to multiple of 32
#define NSP 4
#define NOUT (NTA + NC + NTA*3)   // 263168 f32: en[NTA], E[NC], forces[NTA*3]
#define SORT_CAP (NTA + 4*128)    // 66048 (tiles padded to 128)

// k_main: 128-atom tile, 512 thr (8 waves), 1 block/CU (R17 config, 139us total).
// LDS map (dynamic, 159744 B):
//   [0,2048)          wdT    [256] ushort4
//   [2048,67584)      featB  bf16 [128] rows x 512B, XOR-swz
//   [67584,159744)    dpB    bf16 [128] rows x 720B, linear
//                     Epart  [8][128] f32      (OVERLAY dpB after GEMM2)
//                     Fpart  [8][128][3] f32   (OVERLAY dpB+4096)
#define DP_STRIDE 720
#define LDS_MAIN  159744

typedef __attribute__((ext_vector_type(8))) short short8;
typedef __attribute__((ext_vector_type(4))) float f32x4;

// ---- workspace offsets (bytes) ----
#define OFF_CNT   0
#define OFF_CUR   64
#define OFF_START 128        // 8 ints
#define OFF_FLAG  160        // 1 uint: 1 = float inputs are bf16, 0 = f32
#define OFF_SORT  256        // int[66048] -> ends 264448
#define OFF_B1P   264448     // f32[4*352] -> 270080
#define OFF_W2P   270080     // f32[4*352] -> 275712
#define OFF_W1T   275712     // bf16 [4][352][256] -> 996608
#define OFF_W1P   996608     // bf16 [4][256][352] -> 1717504
#define OFF_SINK  1717504    // f32[131072] diagnostic sink -> 2241792

__device__ __forceinline__ unsigned short f2bf(float f){
  unsigned int u = __builtin_bit_cast(unsigned int, f);
  u += 0x7fffu + ((u>>16)&1u);
  return (unsigned short)(u>>16);
}
__device__ __forceinline__ float bf2f(unsigned short h){
  unsigned int u = ((unsigned int)h)<<16;
  return __builtin_bit_cast(float, u);
}
__device__ __forceinline__ float ldf(const void* p, int idx, int isbf){
  if (isbf) return bf2f(((const unsigned short*)p)[idx]);
  return ((const float*)p)[idx];
}
__device__ __forceinline__ float rcpf(float x){ return __builtin_amdgcn_rcpf(x); }

// init: sorted=-1, species count, dtype probe, zero dout's Ecry slots (replay-safe)
__global__ void k_init2(const int* __restrict__ sym, unsigned int* __restrict__ cnt,
                        int* __restrict__ sorted, const unsigned short* __restrict__ posu,
                        unsigned int* __restrict__ flag, float* __restrict__ dout){
  __shared__ unsigned int h[NSP];
  int t = threadIdx.x;
  if (t < NSP) h[t] = 0u;
  __syncthreads();
  int i = blockIdx.x*256 + t;
  if (i < SORT_CAP) sorted[i] = -1;
  if (i < NC) dout[NTA + i] = 0.f;      // Ecry accumulators live in dout
  if (i < NTA) atomicAdd(&h[sym[i]], 1u);
  __syncthreads();
  if (t < NSP && h[t]) atomicAdd(&cnt[t], h[t]);
  if (blockIdx.x == 257 && t < 64){
    unsigned short u = posu[2*t];
    int e = (u>>7)&0xFF;
    bool inr = (e >= 110 && e <= 140);
    unsigned long long m = __ballot(inr);
    if (t == 0) flag[0] = (__popcll(m) >= 32) ? 1u : 0u;
  }
}

// scatter with inline starts computation (128-padded tiles)
__global__ void k_scatter2(const int* __restrict__ sym, const unsigned int* __restrict__ cnt,
                           unsigned int* __restrict__ cur, int* __restrict__ sorted,
                           int* __restrict__ gstarts){
  __shared__ int sl[NSP+1];
  int t = threadIdx.x;
  if (t == 0){
    int a = 0; sl[0] = 0;
    #pragma unroll
    for (int s=0;s<NSP;s++){ a += (int)(((cnt[s]+127u)>>7)<<7); sl[s+1] = a; }
    if (blockIdx.x == 0){
      #pragma unroll
      for (int s=0;s<=NSP;s++) gstarts[s] = sl[s];
    }
  }
  __syncthreads();
  int i = blockIdx.x*256 + t;
  int s = sym[i];
  int lane = t & 63;
  #pragma unroll
  for (int ss=0; ss<NSP; ss++){
    unsigned long long m = __ballot(s==ss);
    if (s == ss){
      int leader = __builtin_ctzll(m);
      int cw = __popcll(m);
      unsigned int b = 0;
      if (lane == leader) b = atomicAdd(&cur[ss], (unsigned int)cw);
      b = (unsigned int)__shfl((int)b, leader);
      int rank = __popcll(m & ((1ull<<lane) - 1ull));
      sorted[sl[ss] + (int)b + rank] = i;
    }
  }
}

// weight prep via 32x32 LDS transpose tiles: coalesced reads AND writes
__global__ void k_prepw2(const void* __restrict__ W1, const void* __restrict__ b1,
                         const void* __restrict__ W2, const unsigned int* __restrict__ flag,
                         unsigned short* __restrict__ w1t, unsigned short* __restrict__ w1p,
                         float* __restrict__ b1p, float* __restrict__ w2p){
  __shared__ unsigned short T[32][36];
  const int isbf = (int)flag[0];
  const int bid = blockIdx.x;
  const int s  = bid / 88;
  const int jt = (bid % 88) / 8;
  const int it = bid % 8;
  const int t = threadIdx.x;
  {
    const int il = t >> 3;            // 0..31
    const int j4 = (t & 7) * 4;
    const int i = it*32 + il;
    #pragma unroll
    for (int e=0;e<4;e++){
      int j = jt*32 + j4 + e;
      float v = (j < HDIM) ? ldf(W1, (s*NO + i)*HDIM + j, isbf) : 0.f;
      T[il][j4+e] = f2bf(v);
    }
  }
  __syncthreads();
  {
    const int jl = t >> 3;
    const int i4 = (t & 7) * 4;
    ushort4 v; v.x = T[i4][jl]; v.y = T[i4+1][jl]; v.z = T[i4+2][jl]; v.w = T[i4+3][jl];
    *(ushort4*)&w1t[(s*HP + jt*32 + jl)*NO + it*32 + i4] = v;
    const int il = t >> 3;
    const int j4 = (t & 7) * 4;
    ushort4 u; u.x = T[il][j4]; u.y = T[il][j4+1]; u.z = T[il][j4+2]; u.w = T[il][j4+3];
    *(ushort4*)&w1p[(s*NO + it*32 + il)*HP + jt*32 + j4] = u;
  }
  if (it == 0 && t < 32){
    int j = jt*32 + t;
    b1p[s*HP + j] = (j < HDIM) ? ldf(b1, s*HDIM + j, isbf) : 0.f;
    w2p[s*HP + j] = (j < HDIM) ? ldf(W2, s*HDIM + j, isbf) : 0.f;
  }
}

// Fused per-tile kernel, template-phased for rocprof attribution (r19 plan).
// NPH=4: full pipeline (identical to R17 k_main, writes d_out).
// NPH=1: staging only; NPH=2: +GEMM1+epi1; NPH=3: +GEMM2. Diagnostics write only
// to ws sink (DCE-proofed: every accumulator consumed, LDS read back).
// MFMA C/D layout (HW-verified r3 probe): reg q of lane l -> row=(l>>4)*4+q, col=l&15.
template<int NPH>
__global__ __launch_bounds__(512,2) void k_main_t(
    const int* __restrict__ sorted, const int* __restrict__ starts,
    const void* __restrict__ pos, const void* __restrict__ Wd,
    const unsigned short* __restrict__ W1T, const unsigned short* __restrict__ W1P,
    const float* __restrict__ b1p, const float* __restrict__ w2p,
    const void* __restrict__ b2g, const int* __restrict__ crys,
    const unsigned int* __restrict__ flag, float* __restrict__ dout,
    float* __restrict__ sink)
{
  extern __shared__ char smem[];
  ushort4* wdT = (ushort4*)smem;               // [256]
  char* featB  = smem + 2048;                  // bf16 [128] rows x 512B, XOR-swz
  char* dpB    = smem + 2048 + 65536;          // bf16 [128] rows x 720B
  float* Epart = (float*)dpB;                  // overlay after GEMM2: [8][128]
  float* Fpart = (float*)(dpB + 4096);         // overlay: [8][128][3]

  const int base = blockIdx.x*128;
  if (base >= starts[4]) return;
  const int isbf = (int)flag[0];
  int sp = 0;
  #pragma unroll
  for (int s=1;s<NSP;s++) sp = (base >= starts[s]) ? s : sp;

  const int tid = threadIdx.x;
  const int l = tid & 63;
  const int w = tid >> 6;       // 0..7
  const int c = l & 15;
  const int g = l >> 4;

  if (tid < 256){
    float x = ldf(Wd, tid, isbf), y = ldf(Wd, NO+tid, isbf), z = ldf(Wd, 2*NO+tid, isbf);
    ushort4 u; u.x = f2bf(x); u.y = f2bf(y); u.z = f2bf(z); u.w = 0;
    wdT[tid] = u;
  }
  __syncthreads();

  // ---- phase 1: stage feat tile (row m=tid&127, 64-col quarter h=tid>>7) ----
  {
    const int m = tid & 127;
    const int h = tid >> 7;     // 0..3
    int a = sorted[base + m];
    float px=0.f, py=0.f, pz=0.f;
    if (a >= 0){ px = ldf(pos,3*a,isbf); py = ldf(pos,3*a+1,isbf); pz = ldf(pos,3*a+2,isbf); }
    const int swz = (m&7)<<4;
    char* rowp = featB + m*512;
    #pragma unroll
    for (int k8=0;k8<8;k8++){
      int i0 = h*64 + k8*8;
      unsigned int pk[4];
      #pragma unroll
      for (int p2=0;p2<4;p2++){
        unsigned short hv[2];
        #pragma unroll
        for (int e2=0;e2<2;e2++){
          ushort4 wv = wdT[i0 + 2*p2 + e2];
          float v = px*bf2f(wv.x) + py*bf2f(wv.y) + pz*bf2f(wv.z);
          float e = __expf(2.f*v);
          hv[e2] = f2bf(1.f - 2.f*rcpf(e+1.f));   // tanh via rcp
        }
        pk[p2] = (unsigned int)hv[0] | ((unsigned int)hv[1]<<16);
      }
      *(uint4*)(rowp + ((i0*2) ^ swz)) = make_uint4(pk[0],pk[1],pk[2],pk[3]);
    }
  }
  __syncthreads();

  if constexpr (NPH == 1){
    // consume featB (prevents DCE of staging); write sink
    unsigned int v1 = *(unsigned int*)(featB + ((tid*97*4) & 0xFFFC));
    unsigned int v2 = *(unsigned int*)(featB + (((tid*131+977)*4) & 0xFFFC));
    sink[(blockIdx.x*512 + tid) & 0x1FFFF] = (float)(v1 ^ v2);
    return;
  }

  // ---- phase 2: GEMM1 (j-frags: waves 0-5 x3, 6-7 x2) ----
  const unsigned short* W1Ts = W1T + sp*HP*NO;
  const int fr0 = (w<6) ? w*3 : 18 + (w-6)*2;
  const int nT  = (w<6) ? 3 : 2;
  f32x4 acc[3][8];
  #pragma unroll
  for (int t=0;t<3;t++)
    #pragma unroll
    for (int nb=0;nb<8;nb++) acc[t][nb] = f32x4{0.f,0.f,0.f,0.f};

  #pragma unroll
  for (int kk=0; kk<8; kk++){
    short8 bfr[8];
    #pragma unroll
    for (int nb=0;nb<8;nb++){
      int m = nb*16 + c;
      bfr[nb] = *(const short8*)(featB + m*512 + ((kk*64 + g*16) ^ ((m&7)<<4)));
    }
    #pragma unroll
    for (int t=0;t<3;t++){
      if (t < nT){
        const short8 afr = *(const short8*)((const char*)W1Ts + ((fr0+t)*16 + c)*512 + kk*64 + g*16);
        #pragma unroll
        for (int nb=0;nb<8;nb++)
          acc[t][nb] = __builtin_amdgcn_mfma_f32_16x16x32_bf16(afr, bfr[nb], acc[t][nb], 0,0,0);
      }
    }
  }

  // ---- epilogue 1: silu, E partials (regs), dpre -> dpB ----
  const float* b1s = b1p + sp*HP;
  const float* w2s = w2p + sp*HP;
  float esp[8] = {0.f,0.f,0.f,0.f,0.f,0.f,0.f,0.f};
  #pragma unroll
  for (int t=0;t<3;t++){
    if (t < nT){
      const int j0 = (fr0+t)*16 + g*4;
      const float4 b1v = *(const float4*)(b1s + j0);
      const float4 w2v = *(const float4*)(w2s + j0);
      const float* b1a = (const float*)&b1v;
      const float* w2a = (const float*)&w2v;
      #pragma unroll
      for (int nb=0;nb<8;nb++){
        const int m = nb*16 + c;
        unsigned short dph[4];
        #pragma unroll
        for (int q=0;q<4;q++){
          float pre = acc[t][nb][q] + b1a[q];
          float sg = rcpf(1.f + __expf(-pre));     // sigmoid via rcp
          float h = pre*sg;
          esp[nb] += h*w2a[q];
          float dsl = sg*(1.f + pre*(1.f - sg));   // silu'
          dph[q] = f2bf(w2a[q]*dsl);               // dpre
        }
        *(uint2*)(dpB + m*DP_STRIDE + j0*2) =
            make_uint2((unsigned)dph[0] | ((unsigned)dph[1]<<16),
                       (unsigned)dph[2] | ((unsigned)dph[3]<<16));
      }
    }
  }
  float e8[8];
  #pragma unroll
  for (int nb=0;nb<8;nb++){
    float e = esp[nb];
    e += __shfl_xor(e, 16);
    e += __shfl_xor(e, 32);
    e8[nb] = e;                 // valid at g==0
  }
  __syncthreads();   // dpB complete

  if constexpr (NPH == 2){
    float s = e8[0]+e8[1]+e8[2]+e8[3]+e8[4]+e8[5]+e8[6]+e8[7];
    unsigned int v = *(unsigned int*)(dpB + ((tid*181*4) & 0x15FFC));  // < 92160
    sink[(blockIdx.x*512 + tid) & 0x1FFFF] = s + (float)v;
    return;
  }

  // ---- phase 3: GEMM2 (2 i-frags/wave) ----
  const unsigned short* W1Ps = W1P + sp*NO*HP;
  f32x4 acc2[2][8];
  #pragma unroll
  for (int t2=0;t2<2;t2++)
    #pragma unroll
    for (int nb=0;nb<8;nb++) acc2[t2][nb] = f32x4{0.f,0.f,0.f,0.f};

  #pragma unroll
  for (int kk=0; kk<11; kk++){
    short8 bfr[8];
    #pragma unroll
    for (int nb=0;nb<8;nb++){
      int m = nb*16 + c;
      bfr[nb] = *(const short8*)(dpB + m*DP_STRIDE + kk*64 + g*16);
    }
    #pragma unroll
    for (int t2=0;t2<2;t2++){
      const short8 afr = *(const short8*)((const char*)W1Ps + ((2*w+t2)*16 + c)*704 + kk*64 + g*16);
      #pragma unroll
      for (int nb=0;nb<8;nb++)
        acc2[t2][nb] = __builtin_amdgcn_mfma_f32_16x16x32_bf16(afr, bfr[nb], acc2[t2][nb], 0,0,0);
    }
  }

  if constexpr (NPH == 3){
    float s = e8[0]+e8[1]+e8[2]+e8[3]+e8[4]+e8[5]+e8[6]+e8[7];
    #pragma unroll
    for (int t2=0;t2<2;t2++)
      #pragma unroll
      for (int nb=0;nb<8;nb++)
        s += acc2[t2][nb][0]+acc2[t2][nb][1]+acc2[t2][nb][2]+acc2[t2][nb][3];
    sink[(blockIdx.x*512 + tid) & 0x1FFFF] = s;
    return;
  }

  // ---- epilogue 2: dpos = (dfeat * (1-feat^2)) @ Wd^T (featB still alive) ----
  float fax[8], fay[8], faz[8];
  #pragma unroll
  for (int nb=0;nb<8;nb++){ fax[nb]=0.f; fay[nb]=0.f; faz[nb]=0.f; }
  #pragma unroll
  for (int t2=0;t2<2;t2++){
    const int i0 = (2*w+t2)*16 + g*4;
    #pragma unroll
    for (int nb=0;nb<8;nb++){
      const int m = nb*16 + c;
      uint2 fpk = *(const uint2*)(featB + m*512 + ((i0*2) ^ ((m&7)<<4)));
      unsigned short fh[4];
      fh[0] = (unsigned short)(fpk.x & 0xffffu); fh[1] = (unsigned short)(fpk.x >> 16);
      fh[2] = (unsigned short)(fpk.y & 0xffffu); fh[3] = (unsigned short)(fpk.y >> 16);
      #pragma unroll
      for (int q=0;q<4;q++){
        float ff = bf2f(fh[q]);
        float gsc = acc2[t2][nb][q] * (1.f - ff*ff);
        ushort4 wv = wdT[i0 + q];
        fax[nb] += gsc*bf2f(wv.x);
        fay[nb] += gsc*bf2f(wv.y);
        faz[nb] += gsc*bf2f(wv.z);
      }
    }
  }
  #pragma unroll
  for (int nb=0;nb<8;nb++){
    float x = fax[nb], y = fay[nb], z = faz[nb];
    x += __shfl_xor(x, 16); x += __shfl_xor(x, 32);
    y += __shfl_xor(y, 16); y += __shfl_xor(y, 32);
    z += __shfl_xor(z, 16); z += __shfl_xor(z, 32);
    fax[nb] = x; fay[nb] = y; faz[nb] = z;
  }
  __syncthreads();   // all waves done with dpB -> overlay Epart/Fpart

  if (g == 0){
    #pragma unroll
    for (int nb=0;nb<8;nb++){
      const int m = nb*16 + c;
      Epart[w*128 + m] = e8[nb];
      Fpart[(w*128 + m)*3 + 0] = fax[nb];
      Fpart[(w*128 + m)*3 + 1] = fay[nb];
      Fpart[(w*128 + m)*3 + 2] = faz[nb];
    }
  }
  __syncthreads();

  // ---- final: first 128 threads sum 8 wave-partials, write d_out directly ----
  if (tid < 128){
    int a = sorted[base + tid];
    if (a >= 0){
      float E = ldf(b2g, sp, isbf);
      float fx = 0.f, fy = 0.f, fz = 0.f;
      #pragma unroll
      for (int ww=0; ww<8; ww++){
        E  += Epart[ww*128 + tid];
        fx += Fpart[(ww*128 + tid)*3 + 0];
        fy += Fpart[(ww*128 + tid)*3 + 1];
        fz += Fpart[(ww*128 + tid)*3 + 2];
      }
      dout[a] = E;                          // en
      atomicAdd(&dout[NTA + crys[a]], E);   // E (zeroed by k_init2 each call)
      dout[NTA + NC + 3*a + 0] = fx;        // forces
      dout[NTA + NC + 3*a + 1] = fy;
      dout[NTA + NC + 3*a + 2] = fz;
    }
  }
}

extern "C" void kernel_launch(void* const* d_in, const int* in_sizes, int n_in,
                              void* d_out, int out_size, void* d_ws, size_t ws_size,
                              hipStream_t stream) {
  const int*   symbols    = (const int*)  d_in[0];
  const void*  positions  = d_in[1];
  // d_in[2] cells, d_in[3] pbcs, d_in[4] energyidx: unused by the math
  const int*   crystalidx = (const int*)  d_in[5];
  const void*  Wd         = d_in[6];
  const void*  W1         = d_in[7];
  const void*  b1         = d_in[8];
  const void*  W2         = d_in[9];
  const void*  b2         = d_in[10];
  float* dout = (float*)d_out;   // f32 output buffer

  char* ws = (char*)d_ws;
  unsigned int* cnt    = (unsigned int*)(ws + OFF_CNT);
  unsigned int* cur    = (unsigned int*)(ws + OFF_CUR);
  int*          starts = (int*)         (ws + OFF_START);
  unsigned int* flag   = (unsigned int*)(ws + OFF_FLAG);
  int*          sorted = (int*)         (ws + OFF_SORT);
  float*        b1p    = (float*)       (ws + OFF_B1P);
  float*        w2p    = (float*)       (ws + OFF_W2P);
  unsigned short* w1t  = (unsigned short*)(ws + OFF_W1T);
  unsigned short* w1pp = (unsigned short*)(ws + OFF_W1P);
  float*        sink   = (float*)       (ws + OFF_SINK);

  (void)hipFuncSetAttribute((const void*)k_main_t<4>,
                      hipFuncAttributeMaxDynamicSharedMemorySize, LDS_MAIN);
  (void)hipFuncSetAttribute((const void*)k_main_t<1>,
                      hipFuncAttributeMaxDynamicSharedMemorySize, LDS_MAIN);
  (void)hipFuncSetAttribute((const void*)k_main_t<2>,
                      hipFuncAttributeMaxDynamicSharedMemorySize, LDS_MAIN);
  (void)hipFuncSetAttribute((const void*)k_main_t<3>,
                      hipFuncAttributeMaxDynamicSharedMemorySize, LDS_MAIN);

  (void)hipMemsetAsync(ws, 0, 256, stream);           // cnt/cur/starts/flag
  k_init2   <<<258, 256, 0, stream>>>(symbols, cnt, sorted,
                                      (const unsigned short*)positions, flag, dout);
  k_scatter2<<<256, 256, 0, stream>>>(symbols, cnt, cur, sorted, starts);
  k_prepw2  <<<352, 256, 0, stream>>>(W1, b1, W2, flag, w1t, w1pp, b1p, w2p);
  // real pipeline (writes d_out)
  k_main_t<4><<<516, 512, LDS_MAIN, stream>>>(sorted, starts, positions, Wd,
                                              w1t, w1pp, b1p, w2p, b2, crystalidx,
                                              flag, dout, sink);
  // diagnostics (phase-prefix attribution; write only ws sink)
  k_main_t<1><<<516, 512, LDS_MAIN, stream>>>(sorted, starts, positions, Wd,
                                              w1t, w1pp, b1p, w2p, b2, crystalidx,
                                              flag, dout, sink);
  k_main_t<2><<<516, 512, LDS_MAIN, stream>>>(sorted, starts, positions, Wd,
                                              w1t, w1pp, b1p, w2p, b2, crystalidx,
                                              flag, dout, sink);
  k_main_t<3><<<516, 512, LDS_MAIN, stream>>>(sorted, starts, positions, Wd,
                                              w1t, w1pp, b1p, w2p, b2, crystalidx,
                                              flag, dout, sink);
}

// Round 22
// 161.252 us; speedup vs baseline: 1.6660x; 1.6660x over previous
//
#include <hip/hip_runtime.h>

#define NTA 65536
#define NC 1024
#define NO 256
#define HDIM 332
#define HP 352          // H padded to multiple of 32
#define NSP 4
#define NOUT (NTA + NC + NTA*3)   // 263168 f32: en[NTA], E[NC], forces[NTA*3]
#define SORT_CAP (NTA + 4*128)    // 66048 (tiles padded to 128)

// k_main v9: 128-atom tile, 512 thr (8 waves), 1 block/CU.
// A-panels stream via global_load_lds (async DMA, ~1400 16B chunks in flight)
// into double-buffered per-kk LDS slices. LDS map (dynamic, 126976 B):
//   phase GEMM1: [0,2048) wdT | [2048,67584) featB (bf16 [128]x512B, XOR-swz)
//                | [67584,90112) A1 buf0 (22528) | [90112,112640) A1 buf1
//   phase GEMM2 (overlay): [2048,94208) dpB (bf16 [128]x720B, linear)
//                | [94208,110592) A2 buf0 (16384) | [110592,126976) A2 buf1
//   epilogue (overlay dpB): Epart [8][128] f32 @2048; Fpart [8][128][3] @6144
#define LDS_FEATB 2048
#define LDS_A1B0  67584
#define LDS_A1B1  90112
#define LDS_DPB   2048
#define LDS_A2B0  94208
#define LDS_A2B1  110592
#define LDS_MAIN  126976
#define DP_STRIDE 720

typedef __attribute__((ext_vector_type(8))) short short8;
typedef __attribute__((ext_vector_type(4))) float f32x4;

// ---- workspace offsets (bytes) ----
#define OFF_CNT   0
#define OFF_CUR   64
#define OFF_START 128        // 8 ints
#define OFF_FLAG  160        // 1 uint: 1 = float inputs are bf16, 0 = f32
#define OFF_SORT  256        // int[66048] -> ends 264448
#define OFF_B1P   264448     // f32[4*352] -> 270080
#define OFF_W2P   270080     // f32[4*352] -> 275712
#define OFF_W1T   275712     // bf16 [4][352][256] -> 996608
#define OFF_W1P   996608     // bf16 [4][256][352] -> 1717504

__device__ __forceinline__ unsigned short f2bf(float f){
  unsigned int u = __builtin_bit_cast(unsigned int, f);
  u += 0x7fffu + ((u>>16)&1u);
  return (unsigned short)(u>>16);
}
__device__ __forceinline__ float bf2f(unsigned short h){
  unsigned int u = ((unsigned int)h)<<16;
  return __builtin_bit_cast(float, u);
}
__device__ __forceinline__ float ldf(const void* p, int idx, int isbf){
  if (isbf) return bf2f(((const unsigned short*)p)[idx]);
  return ((const float*)p)[idx];
}
__device__ __forceinline__ float rcpf(float x){ return __builtin_amdgcn_rcpf(x); }

// async 16B global->LDS (no VGPR destination; deep vmcnt queue).
// LDS dest pattern = wave-uniform base + lane*16 (the supported layout).
__device__ __forceinline__ void gld16(const void* g, void* l){
  __builtin_amdgcn_global_load_lds(
      (const __attribute__((address_space(1))) void*)g,
      (__attribute__((address_space(3))) void*)l, 16, 0, 0);
}

// init: sorted=-1, species count, dtype probe, zero dout's Ecry slots (replay-safe)
__global__ void k_init2(const int* __restrict__ sym, unsigned int* __restrict__ cnt,
                        int* __restrict__ sorted, const unsigned short* __restrict__ posu,
                        unsigned int* __restrict__ flag, float* __restrict__ dout){
  __shared__ unsigned int h[NSP];
  int t = threadIdx.x;
  if (t < NSP) h[t] = 0u;
  __syncthreads();
  int i = blockIdx.x*256 + t;
  if (i < SORT_CAP) sorted[i] = -1;
  if (i < NC) dout[NTA + i] = 0.f;      // Ecry accumulators live in dout
  if (i < NTA) atomicAdd(&h[sym[i]], 1u);
  __syncthreads();
  if (t < NSP && h[t]) atomicAdd(&cnt[t], h[t]);
  if (blockIdx.x == 257 && t < 64){
    unsigned short u = posu[2*t];
    int e = (u>>7)&0xFF;
    bool inr = (e >= 110 && e <= 140);
    unsigned long long m = __ballot(inr);
    if (t == 0) flag[0] = (__popcll(m) >= 32) ? 1u : 0u;
  }
}

// scatter with inline starts computation (128-padded tiles)
__global__ void k_scatter2(const int* __restrict__ sym, const unsigned int* __restrict__ cnt,
                           unsigned int* __restrict__ cur, int* __restrict__ sorted,
                           int* __restrict__ gstarts){
  __shared__ int sl[NSP+1];
  int t = threadIdx.x;
  if (t == 0){
    int a = 0; sl[0] = 0;
    #pragma unroll
    for (int s=0;s<NSP;s++){ a += (int)(((cnt[s]+127u)>>7)<<7); sl[s+1] = a; }
    if (blockIdx.x == 0){
      #pragma unroll
      for (int s=0;s<=NSP;s++) gstarts[s] = sl[s];
    }
  }
  __syncthreads();
  int i = blockIdx.x*256 + t;
  int s = sym[i];
  int lane = t & 63;
  #pragma unroll
  for (int ss=0; ss<NSP; ss++){
    unsigned long long m = __ballot(s==ss);
    if (s == ss){
      int leader = __builtin_ctzll(m);
      int cw = __popcll(m);
      unsigned int b = 0;
      if (lane == leader) b = atomicAdd(&cur[ss], (unsigned int)cw);
      b = (unsigned int)__shfl((int)b, leader);
      int rank = __popcll(m & ((1ull<<lane) - 1ull));
      sorted[sl[ss] + (int)b + rank] = i;
    }
  }
}

// weight prep via 32x32 LDS transpose tiles: coalesced reads AND writes
__global__ void k_prepw2(const void* __restrict__ W1, const void* __restrict__ b1,
                         const void* __restrict__ W2, const unsigned int* __restrict__ flag,
                         unsigned short* __restrict__ w1t, unsigned short* __restrict__ w1p,
                         float* __restrict__ b1p, float* __restrict__ w2p){
  __shared__ unsigned short T[32][36];
  const int isbf = (int)flag[0];
  const int bid = blockIdx.x;
  const int s  = bid / 88;
  const int jt = (bid % 88) / 8;
  const int it = bid % 8;
  const int t = threadIdx.x;
  {
    const int il = t >> 3;            // 0..31
    const int j4 = (t & 7) * 4;
    const int i = it*32 + il;
    #pragma unroll
    for (int e=0;e<4;e++){
      int j = jt*32 + j4 + e;
      float v = (j < HDIM) ? ldf(W1, (s*NO + i)*HDIM + j, isbf) : 0.f;
      T[il][j4+e] = f2bf(v);
    }
  }
  __syncthreads();
  {
    const int jl = t >> 3;
    const int i4 = (t & 7) * 4;
    ushort4 v; v.x = T[i4][jl]; v.y = T[i4+1][jl]; v.z = T[i4+2][jl]; v.w = T[i4+3][jl];
    *(ushort4*)&w1t[(s*HP + jt*32 + jl)*NO + it*32 + i4] = v;
    const int il = t >> 3;
    const int j4 = (t & 7) * 4;
    ushort4 u; u.x = T[il][j4]; u.y = T[il][j4+1]; u.z = T[il][j4+2]; u.w = T[il][j4+3];
    *(ushort4*)&w1p[(s*NO + it*32 + il)*HP + jt*32 + j4] = u;
  }
  if (it == 0 && t < 32){
    int j = jt*32 + t;
    b1p[s*HP + j] = (j < HDIM) ? ldf(b1, s*HDIM + j, isbf) : 0.f;
    w2p[s*HP + j] = (j < HDIM) ? ldf(W2, s*HDIM + j, isbf) : 0.f;
  }
}

// A1 slice kk (22528 B = 1408 chunks): chunk p -> row p>>2, 16B-group p&3.
#define ISSUE_A1(dstbuf, kk) do{                                               \
    int p_ = tid;                                                              \
    gld16(W1Tb + (p_>>2)*512 + (kk)*64 + (p_&3)*16, (dstbuf) + p_*16);         \
    p_ = tid + 512;                                                            \
    gld16(W1Tb + (p_>>2)*512 + (kk)*64 + (p_&3)*16, (dstbuf) + p_*16);         \
    if (w < 6){ p_ = tid + 1024;                                               \
      gld16(W1Tb + (p_>>2)*512 + (kk)*64 + (p_&3)*16, (dstbuf) + p_*16); }     \
  }while(0)

// A2 slice kk (16384 B = 1024 chunks)
#define ISSUE_A2(dstbuf, kk) do{                                               \
    int p_ = tid;                                                              \
    gld16(W1Pb + (p_>>2)*704 + (kk)*64 + (p_&3)*16, (dstbuf) + p_*16);         \
    p_ = tid + 512;                                                            \
    gld16(W1Pb + (p_>>2)*704 + (kk)*64 + (p_&3)*16, (dstbuf) + p_*16);         \
  }while(0)

// MFMA C/D layout (HW-verified r3 probe): reg q of lane l -> row=(l>>4)*4+q, col=l&15.
__global__ __launch_bounds__(512,2) void k_main(
    const int* __restrict__ sorted, const int* __restrict__ starts,
    const void* __restrict__ pos, const void* __restrict__ Wd,
    const unsigned short* __restrict__ W1T, const unsigned short* __restrict__ W1P,
    const float* __restrict__ b1p, const float* __restrict__ w2p,
    const void* __restrict__ b2g, const int* __restrict__ crys,
    const unsigned int* __restrict__ flag, float* __restrict__ dout)
{
  extern __shared__ char smem[];
  ushort4* wdT = (ushort4*)smem;
  char* featB = smem + LDS_FEATB;
  char* a1b0  = smem + LDS_A1B0;
  char* a1b1  = smem + LDS_A1B1;
  char* dpB   = smem + LDS_DPB;     // overlay (featB+A1 dead after GEMM1)
  char* a2b0  = smem + LDS_A2B0;
  char* a2b1  = smem + LDS_A2B1;
  float* Epart = (float*)(smem + LDS_DPB);          // overlay after GEMM2
  float* Fpart = (float*)(smem + LDS_DPB + 4096);

  const int base = blockIdx.x*128;
  if (base >= starts[4]) return;
  const int isbf = (int)flag[0];
  int sp = 0;
  #pragma unroll
  for (int s=1;s<NSP;s++) sp = (base >= starts[s]) ? s : sp;

  const int tid = threadIdx.x;
  const int l = tid & 63;
  const int w = tid >> 6;       // 0..7
  const int c = l & 15;
  const int g = l >> 4;

  const unsigned short* W1Ts = W1T + sp*HP*NO;
  const unsigned short* W1Ps = W1P + sp*NO*HP;
  const char* W1Tb = (const char*)W1Ts;
  const char* W1Pb = (const char*)W1Ps;

  if (tid < 256){
    float x = ldf(Wd, tid, isbf), y = ldf(Wd, NO+tid, isbf), z = ldf(Wd, 2*NO+tid, isbf);
    ushort4 u; u.x = f2bf(x); u.y = f2bf(y); u.z = f2bf(z); u.w = 0;
    wdT[tid] = u;
  }
  __syncthreads();

  // issue A1 slices 0,1 (lands under tanh staging; drained by next barrier)
  ISSUE_A1(a1b0, 0);
  ISSUE_A1(a1b1, 1);

  // ---- phase 1: stage feat tile (row m=tid&127, 64-col quarter h=tid>>7) ----
  {
    const int m = tid & 127;
    const int h = tid >> 7;     // 0..3
    int a = sorted[base + m];
    float px=0.f, py=0.f, pz=0.f;
    if (a >= 0){ px = ldf(pos,3*a,isbf); py = ldf(pos,3*a+1,isbf); pz = ldf(pos,3*a+2,isbf); }
    const int swz = (m&7)<<4;
    char* rowp = featB + m*512;
    #pragma unroll
    for (int k8=0;k8<8;k8++){
      int i0 = h*64 + k8*8;
      unsigned int pk[4];
      #pragma unroll
      for (int p2=0;p2<4;p2++){
        unsigned short hv[2];
        #pragma unroll
        for (int e2=0;e2<2;e2++){
          ushort4 wv = wdT[i0 + 2*p2 + e2];
          float v = px*bf2f(wv.x) + py*bf2f(wv.y) + pz*bf2f(wv.z);
          float e = __expf(2.f*v);
          hv[e2] = f2bf(1.f - 2.f*rcpf(e+1.f));   // tanh via rcp
        }
        pk[p2] = (unsigned int)hv[0] | ((unsigned int)hv[1]<<16);
      }
      *(uint4*)(rowp + ((i0*2) ^ swz)) = make_uint4(pk[0],pk[1],pk[2],pk[3]);
    }
  }
  __syncthreads();   // featB ready; A1 slices 0,1 drained

  // ---- phase 2: GEMM1 (j-frags: waves 0-5 x3, 6-7 x2), A from LDS dbuf ----
  const int fr0 = (w<6) ? w*3 : 18 + (w-6)*2;
  const int nT  = (w<6) ? 3 : 2;
  f32x4 acc[3][8];
  #pragma unroll
  for (int t=0;t<3;t++)
    #pragma unroll
    for (int nb=0;nb<8;nb++) acc[t][nb] = f32x4{0.f,0.f,0.f,0.f};

  #pragma unroll
  for (int j=0;j<8;j++){
    char* ab = (j&1) ? a1b1 : a1b0;
    short8 bfr[8];
    #pragma unroll
    for (int nb=0;nb<8;nb++){
      int m = nb*16 + c;
      bfr[nb] = *(const short8*)(featB + m*512 + ((j*64 + g*16) ^ ((m&7)<<4)));
    }
    short8 afr[3];
    #pragma unroll
    for (int t=0;t<3;t++)
      if (t < nT) afr[t] = *(const short8*)(ab + ((fr0+t)*16 + c)*64 + g*16);
    #pragma unroll
    for (int t=0;t<3;t++){
      if (t < nT){
        #pragma unroll
        for (int nb=0;nb<8;nb++)
          acc[t][nb] = __builtin_amdgcn_mfma_f32_16x16x32_bf16(afr[t], bfr[nb], acc[t][nb], 0,0,0);
      }
    }
    __syncthreads();                 // all waves done reading ab
    if (j < 6) ISSUE_A1(ab, j+2);    // refill the buffer just retired
  }

  // ---- epilogue 1: issue A2 slices; silu, E partials (regs), dpre -> dpB ----
  ISSUE_A2(a2b0, 0);
  ISSUE_A2(a2b1, 1);
  const float* b1s = b1p + sp*HP;
  const float* w2s = w2p + sp*HP;
  float esp[8] = {0.f,0.f,0.f,0.f,0.f,0.f,0.f,0.f};
  #pragma unroll
  for (int t=0;t<3;t++){
    if (t < nT){
      const int j0 = (fr0+t)*16 + g*4;
      const float4 b1v = *(const float4*)(b1s + j0);
      const float4 w2v = *(const float4*)(w2s + j0);
      const float* b1a = (const float*)&b1v;
      const float* w2a = (const float*)&w2v;
      #pragma unroll
      for (int nb=0;nb<8;nb++){
        const int m = nb*16 + c;
        unsigned short dph[4];
        #pragma unroll
        for (int q=0;q<4;q++){
          float pre = acc[t][nb][q] + b1a[q];
          float sg = rcpf(1.f + __expf(-pre));     // sigmoid via rcp
          float h = pre*sg;
          esp[nb] += h*w2a[q];
          float dsl = sg*(1.f + pre*(1.f - sg));   // silu'
          dph[q] = f2bf(w2a[q]*dsl);               // dpre
        }
        *(uint2*)(dpB + m*DP_STRIDE + j0*2) =
            make_uint2((unsigned)dph[0] | ((unsigned)dph[1]<<16),
                       (unsigned)dph[2] | ((unsigned)dph[3]<<16));
      }
    }
  }
  float e8[8];
  #pragma unroll
  for (int nb=0;nb<8;nb++){
    float e = esp[nb];
    e += __shfl_xor(e, 16);
    e += __shfl_xor(e, 32);
    e8[nb] = e;                 // valid at g==0; held through GEMM2
  }
  __syncthreads();   // dpB complete; A2 slices 0,1 drained

  // ---- phase 3: GEMM2 (2 i-frags/wave), A from LDS dbuf ----
  f32x4 acc2[2][8];
  #pragma unroll
  for (int t2=0;t2<2;t2++)
    #pragma unroll
    for (int nb=0;nb<8;nb++) acc2[t2][nb] = f32x4{0.f,0.f,0.f,0.f};

  #pragma unroll
  for (int j=0;j<11;j++){
    char* ab = (j&1) ? a2b1 : a2b0;
    short8 bfr[8];
    #pragma unroll
    for (int nb=0;nb<8;nb++){
      int m = nb*16 + c;
      bfr[nb] = *(const short8*)(dpB + m*DP_STRIDE + j*64 + g*16);
    }
    short8 afr2[2];
    #pragma unroll
    for (int t2=0;t2<2;t2++)
      afr2[t2] = *(const short8*)(ab + ((2*w+t2)*16 + c)*64 + g*16);
    #pragma unroll
    for (int t2=0;t2<2;t2++){
      #pragma unroll
      for (int nb=0;nb<8;nb++)
        acc2[t2][nb] = __builtin_amdgcn_mfma_f32_16x16x32_bf16(afr2[t2], bfr[nb], acc2[t2][nb], 0,0,0);
    }
    __syncthreads();
    if (j < 9) ISSUE_A2(ab, j+2);
  }

  // ---- epilogue 2: recompute f=tanh (featB dead); dpos=(dfeat*(1-f^2))@Wd^T ----
  int a8[8]; float px8[8], py8[8], pz8[8];
  #pragma unroll
  for (int nb=0;nb<8;nb++){
    int aa = sorted[base + nb*16 + c];
    a8[nb] = aa;
    float x=0.f,y=0.f,z=0.f;
    if (aa >= 0){ x=ldf(pos,3*aa,isbf); y=ldf(pos,3*aa+1,isbf); z=ldf(pos,3*aa+2,isbf); }
    px8[nb]=x; py8[nb]=y; pz8[nb]=z;
  }
  float fax[8], fay[8], faz[8];
  #pragma unroll
  for (int nb=0;nb<8;nb++){ fax[nb]=0.f; fay[nb]=0.f; faz[nb]=0.f; }
  #pragma unroll
  for (int t2=0;t2<2;t2++){
    const int i0 = (2*w+t2)*16 + g*4;
    #pragma unroll
    for (int q=0;q<4;q++){
      ushort4 wv = wdT[i0 + q];
      float wx = bf2f(wv.x), wy = bf2f(wv.y), wz = bf2f(wv.z);
      #pragma unroll
      for (int nb=0;nb<8;nb++){
        float v = px8[nb]*wx + py8[nb]*wy + pz8[nb]*wz;
        float e = __expf(2.f*v);
        float f = 1.f - 2.f*rcpf(e+1.f);
        float gsc = acc2[t2][nb][q] * (1.f - f*f);
        fax[nb] += gsc*wx;
        fay[nb] += gsc*wy;
        faz[nb] += gsc*wz;
      }
    }
  }
  #pragma unroll
  for (int nb=0;nb<8;nb++){
    float x = fax[nb], y = fay[nb], z = faz[nb];
    x += __shfl_xor(x, 16); x += __shfl_xor(x, 32);
    y += __shfl_xor(y, 16); y += __shfl_xor(y, 32);
    z += __shfl_xor(z, 16); z += __shfl_xor(z, 32);
    fax[nb] = x; fay[nb] = y; faz[nb] = z;
  }
  __syncthreads();   // GEMM2 fully done -> overlay Epart/Fpart over dpB

  if (g == 0){
    #pragma unroll
    for (int nb=0;nb<8;nb++){
      const int m = nb*16 + c;
      Epart[w*128 + m] = e8[nb];
      Fpart[(w*128 + m)*3 + 0] = fax[nb];
      Fpart[(w*128 + m)*3 + 1] = fay[nb];
      Fpart[(w*128 + m)*3 + 2] = faz[nb];
    }
  }
  __syncthreads();

  // ---- final: first 128 threads sum 8 wave-partials, write d_out directly ----
  if (tid < 128){
    int a = sorted[base + tid];
    if (a >= 0){
      float E = ldf(b2g, sp, isbf);
      float fx = 0.f, fy = 0.f, fz = 0.f;
      #pragma unroll
      for (int ww=0; ww<8; ww++){
        E  += Epart[ww*128 + tid];
        fx += Fpart[(ww*128 + tid)*3 + 0];
        fy += Fpart[(ww*128 + tid)*3 + 1];
        fz += Fpart[(ww*128 + tid)*3 + 2];
      }
      dout[a] = E;                          // en
      atomicAdd(&dout[NTA + crys[a]], E);   // E (zeroed by k_init2 each call)
      dout[NTA + NC + 3*a + 0] = fx;        // forces
      dout[NTA + NC + 3*a + 1] = fy;
      dout[NTA + NC + 3*a + 2] = fz;
    }
  }
}

extern "C" void kernel_launch(void* const* d_in, const int* in_sizes, int n_in,
                              void* d_out, int out_size, void* d_ws, size_t ws_size,
                              hipStream_t stream) {
  const int*   symbols    = (const int*)  d_in[0];
  const void*  positions  = d_in[1];
  // d_in[2] cells, d_in[3] pbcs, d_in[4] energyidx: unused by the math
  const int*   crystalidx = (const int*)  d_in[5];
  const void*  Wd         = d_in[6];
  const void*  W1         = d_in[7];
  const void*  b1         = d_in[8];
  const void*  W2         = d_in[9];
  const void*  b2         = d_in[10];
  float* dout = (float*)d_out;   // f32 output buffer

  char* ws = (char*)d_ws;
  unsigned int* cnt    = (unsigned int*)(ws + OFF_CNT);
  unsigned int* cur    = (unsigned int*)(ws + OFF_CUR);
  int*          starts = (int*)         (ws + OFF_START);
  unsigned int* flag   = (unsigned int*)(ws + OFF_FLAG);
  int*          sorted = (int*)         (ws + OFF_SORT);
  float*        b1p    = (float*)       (ws + OFF_B1P);
  float*        w2p    = (float*)       (ws + OFF_W2P);
  unsigned short* w1t  = (unsigned short*)(ws + OFF_W1T);
  unsigned short* w1pp = (unsigned short*)(ws + OFF_W1P);

  (void)hipFuncSetAttribute((const void*)k_main,
                      hipFuncAttributeMaxDynamicSharedMemorySize, LDS_MAIN);

  (void)hipMemsetAsync(ws, 0, 256, stream);           // cnt/cur/starts/flag
  k_init2   <<<258, 256, 0, stream>>>(symbols, cnt, sorted,
                                      (const unsigned short*)positions, flag, dout);
  k_scatter2<<<256, 256, 0, stream>>>(symbols, cnt, cur, sorted, starts);
  k_prepw2  <<<352, 256, 0, stream>>>(W1, b1, W2, flag, w1t, w1pp, b1p, w2p);
  k_main    <<<516, 512, LDS_MAIN, stream>>>(sorted, starts, positions, Wd,
                                             w1t, w1pp, b1p, w2p, b2, crystalidx,
                                             flag, dout);
}